// Round 1
// baseline (351.012 us; speedup 1.0000x reference)
//
#include <hip/hip_runtime.h>
#include <math.h>

#define BB 128
#define CIN 512
#define HW 64
#define OUTC 256
#define EMB 4096
#define DDIM 4096
#define NPIX 8192
#define ES 32

// workspace layout (float offsets)
#define FT_OFF    0          // 8192*256 floats
#define ENC_OFF   2097152    // 8192 ints
#define TSUM_OFF  2105344    // 4096
#define TLOGT_OFF 2109440    // 4096
#define PM_OFF    2113536    // 4*128*64
#define PL_OFF    2146304
#define PD_OFF    2179072

// ---------------- K1: ft[n][o] = feature(b,:,p) . W[o,:] + bias[o] ----------
__global__ __launch_bounds__(256) void k_lda(const float* __restrict__ feat,
                                             const float* __restrict__ w,
                                             const float* __restrict__ bias,
                                             float* __restrict__ ft) {
    __shared__ __align__(16) float As[16 * 64];
    __shared__ __align__(16) float Bs[16 * 64];
    int bx = blockIdx.x;
    int nb = bx >> 2, ob = bx & 3;           // 128 n-tiles (one batch each), 4 o-tiles
    int n0 = nb * 64, o0 = ob * 64;
    int tid = threadIdx.x;
    int tx = tid & 15, ty = tid >> 4;        // tx -> o dir, ty -> pixel dir
    float acc[4][4] = {};
    const float* fbase = feat + (size_t)nb * CIN * HW;
    for (int kt = 0; kt < CIN / 16; ++kt) {
        int c0 = kt * 16;
        {   // A tile: 16c x 64p, contiguous in memory
            int idx = tid * 4;
            *(float4*)&As[idx] = *(const float4*)&fbase[c0 * 64 + idx];
        }
        {   // B tile: w rows o0..o0+63, cols c0..c0+15, store transposed [k][o]
            int oo = tid & 63, kq = tid >> 6;
            float4 wv = *(const float4*)&w[(size_t)(o0 + oo) * CIN + c0 + kq * 4];
            Bs[(kq * 4 + 0) * 64 + oo] = wv.x;
            Bs[(kq * 4 + 1) * 64 + oo] = wv.y;
            Bs[(kq * 4 + 2) * 64 + oo] = wv.z;
            Bs[(kq * 4 + 3) * 64 + oo] = wv.w;
        }
        __syncthreads();
#pragma unroll
        for (int k = 0; k < 16; ++k) {
            float4 a4 = *(float4*)&As[k * 64 + ty * 4];
            float4 b4 = *(float4*)&Bs[k * 64 + tx * 4];
            float av[4] = {a4.x, a4.y, a4.z, a4.w};
            float bv[4] = {b4.x, b4.y, b4.z, b4.w};
#pragma unroll
            for (int i = 0; i < 4; ++i)
#pragma unroll
                for (int j = 0; j < 4; ++j)
                    acc[i][j] = fmaf(av[i], bv[j], acc[i][j]);
        }
        __syncthreads();
    }
    float4 bs4 = *(const float4*)&bias[o0 + tx * 4];
    float bv[4] = {bs4.x, bs4.y, bs4.z, bs4.w};
#pragma unroll
    for (int i = 0; i < 4; ++i) {
        float4 v;
        v.x = acc[i][0] + bv[0];
        v.y = acc[i][1] + bv[1];
        v.z = acc[i][2] + bv[2];
        v.w = acc[i][3] + bv[3];
        *(float4*)&ft[(size_t)(n0 + ty * 4 + i) * OUTC + o0 + tx * 4] = v;
    }
}

// ---------------- K2: enc[n] = cls*32 + argmin_j ||ft_n - c_j||^2 -----------
__global__ __launch_bounds__(256) void k_enc(const float* __restrict__ ft,
                                             const float* __restrict__ cc,
                                             const int* __restrict__ labels,
                                             int* __restrict__ enc) {
    __shared__ __align__(16) float cbuf[ES * OUTC];   // 32 KB
    __shared__ float vred[4 * 64];
    __shared__ int   ired[4 * 64];
    int b = blockIdx.x, tid = threadIdx.x;
    int cls = labels[b];
    const float* cbase = cc + (size_t)cls * ES * OUTC;
    for (int i = tid * 4; i < ES * OUTC; i += 256 * 4)
        *(float4*)&cbuf[i] = *(const float4*)&cbase[i];
    __syncthreads();
    int p = tid & 63, jg = tid >> 6;     // each thread: pixel p, subclasses jg*8..jg*8+7
    const float* xrow = ft + (size_t)(b * 64 + p) * OUTC;
    float sc[8];
#pragma unroll
    for (int jj = 0; jj < 8; ++jj) sc[jj] = 0.f;
    for (int o = 0; o < OUTC; o += 4) {
        float4 x4 = *(const float4*)&xrow[o];
        float m0 = -2.f * x4.x, m1 = -2.f * x4.y, m2 = -2.f * x4.z, m3 = -2.f * x4.w;
#pragma unroll
        for (int jj = 0; jj < 8; ++jj) {
            const float* cr = &cbuf[(jg * 8 + jj) * OUTC + o];
            float s = sc[jj];
            s = fmaf(cr[0], cr[0] + m0, s);
            s = fmaf(cr[1], cr[1] + m1, s);
            s = fmaf(cr[2], cr[2] + m2, s);
            s = fmaf(cr[3], cr[3] + m3, s);
            sc[jj] = s;
        }
    }
    // local argmin, ascending j, strict <  (matches jnp.argmax first-max)
    float best = sc[0]; int bj = jg * 8;
#pragma unroll
    for (int jj = 1; jj < 8; ++jj)
        if (sc[jj] < best) { best = sc[jj]; bj = jg * 8 + jj; }
    vred[jg * 64 + p] = best;
    ired[jg * 64 + p] = bj;
    __syncthreads();
    if (tid < 64) {
        float bv = vred[tid]; int bi = ired[tid];
#pragma unroll
        for (int g = 1; g < 4; ++g) {
            float v = vred[g * 64 + tid];
            if (v < bv) { bv = v; bi = ired[g * 64 + tid]; }
        }
        enc[b * 64 + tid] = cls * ES + bi;
    }
}

// ---------------- K3: per-row sums of teacher_scores ------------------------
__global__ __launch_bounds__(256) void k_rowsum(const float* __restrict__ ts,
                                                float* __restrict__ tsum,
                                                float* __restrict__ tlogt) {
    int e = blockIdx.x, tid = threadIdx.x;
    const float* row = ts + (size_t)e * DDIM;
    float st = 0.f, sl = 0.f;
#pragma unroll
    for (int i = 0; i < 4; ++i) {
        float4 t4 = *(const float4*)&row[tid * 4 + i * 1024];
        float tv[4] = {t4.x, t4.y, t4.z, t4.w};
#pragma unroll
        for (int j = 0; j < 4; ++j) {
            float t = tv[j];
            st += t;
            sl += (t > 0.f) ? t * logf(t) : 0.f;
        }
    }
    for (int off = 32; off; off >>= 1) {
        st += __shfl_down(st, off);
        sl += __shfl_down(sl, off);
    }
    __shared__ float r[8];
    int lane = tid & 63, wv = tid >> 6;
    if (lane == 0) { r[wv] = st; r[4 + wv] = sl; }
    __syncthreads();
    if (tid == 0) {
        tsum[e]  = r[0] + r[1] + r[2] + r[3];
        tlogt[e] = r[4] + r[5] + r[6] + r[7];
    }
}

// ---------------- K4a: per (b, quarter-of-D): max, sumexp, dot --------------
__global__ __launch_bounds__(256) void k_main(const float* __restrict__ scores,
                                              const float* __restrict__ ts,
                                              const int* __restrict__ enc,
                                              float* __restrict__ pm,
                                              float* __restrict__ pl,
                                              float* __restrict__ pd) {
    __shared__ int enc_s[64];
    __shared__ float red[4 * 64];
    int bx = blockIdx.x;
    int b = bx >> 2, q = bx & 3;
    int tid = threadIdx.x, p = tid & 63, wv = tid >> 6;
    if (tid < 64) enc_s[tid] = enc[b * 64 + tid];
    __syncthreads();
    size_t ebase = (size_t)enc_s[p] * DDIM;
    const float* sbase = scores + (size_t)b * DDIM * 64 + (size_t)q * 1024 * 64;
    const float* trow  = ts + ebase + q * 1024;
    float m = -INFINITY, dot = 0.f;
#pragma unroll 8
    for (int dd = 0; dd < 256; ++dd) {
        int dl = dd * 4 + wv;
        float s = sbase[(size_t)dl * 64 + p];
        float t = trow[dl];
        m = fmaxf(m, s);
        dot = fmaf(t, s, dot);
    }
    red[wv * 64 + p] = m;
    __syncthreads();
    float M = fmaxf(fmaxf(red[p], red[64 + p]), fmaxf(red[128 + p], red[192 + p]));
    __syncthreads();
    float l = 0.f;
#pragma unroll 8
    for (int dd = 0; dd < 256; ++dd) {
        int dl = dd * 4 + wv;
        float s = sbase[(size_t)dl * 64 + p];
        l += __expf(s - M);
    }
    red[wv * 64 + p] = l;
    __syncthreads();
    float L = red[p] + red[64 + p] + red[128 + p] + red[192 + p];
    __syncthreads();
    red[wv * 64 + p] = dot;
    __syncthreads();
    if (tid < 64) {
        float D = red[tid] + red[64 + tid] + red[128 + tid] + red[192 + tid];
        int idx = (b * 4 + q) * 64 + tid;
        pm[idx] = M;     // tid<64 -> p==tid, M valid for this pixel
        pl[idx] = L;
        pd[idx] = D;
    }
}

// ---------------- K4b: merge partials, final loss ---------------------------
__global__ __launch_bounds__(64) void k_final(const float* __restrict__ pm,
                                              const float* __restrict__ pl,
                                              const float* __restrict__ pd,
                                              const int* __restrict__ enc,
                                              const float* __restrict__ tsum,
                                              const float* __restrict__ tlogt,
                                              float* __restrict__ out) {
    int b = blockIdx.x, p = threadIdx.x;
    int base = b * 4 * 64 + p;
    float M = -INFINITY;
#pragma unroll
    for (int q = 0; q < 4; ++q) M = fmaxf(M, pm[base + q * 64]);
    float L = 0.f, D = 0.f;
#pragma unroll
    for (int q = 0; q < 4; ++q) {
        L += pl[base + q * 64] * __expf(pm[base + q * 64] - M);
        D += pd[base + q * 64];
    }
    float lse = M + logf(L);
    int e = enc[b * 64 + p];
    float row = tlogt[e] - D + tsum[e] * lse;
    for (int off = 32; off; off >>= 1) row += __shfl_down(row, off);
    if (p == 0) atomicAdd(out, row * (1.f / 8192.f));
}

extern "C" void kernel_launch(void* const* d_in, const int* in_sizes, int n_in,
                              void* d_out, int out_size, void* d_ws, size_t ws_size,
                              hipStream_t stream) {
    const float* feat   = (const float*)d_in[0];
    const float* scores = (const float*)d_in[1];
    const int*   labels = (const int*)d_in[2];
    const float* ldaw   = (const float*)d_in[3];
    const float* ldab   = (const float*)d_in[4];
    const float* cc     = (const float*)d_in[5];
    const float* ts     = (const float*)d_in[6];
    float* out = (float*)d_out;
    float* ws  = (float*)d_ws;

    float* ft    = ws + FT_OFF;
    int*   enc   = (int*)(ws + ENC_OFF);
    float* tsum  = ws + TSUM_OFF;
    float* tlogt = ws + TLOGT_OFF;
    float* pm    = ws + PM_OFF;
    float* pl    = ws + PL_OFF;
    float* pd    = ws + PD_OFF;

    hipMemsetAsync(out, 0, sizeof(float), stream);

    k_lda   <<<512,  256, 0, stream>>>(feat, ldaw, ldab, ft);
    k_enc   <<<BB,   256, 0, stream>>>(ft, cc, labels, enc);
    k_rowsum<<<EMB,  256, 0, stream>>>(ts, tsum, tlogt);
    k_main  <<<512,  256, 0, stream>>>(scores, ts, enc, pm, pl, pd);
    k_final <<<BB,    64, 0, stream>>>(pm, pl, pd, enc, tsum, tlogt, out);
}

// Round 2
// 333.324 us; speedup vs baseline: 1.0531x; 1.0531x over previous
//
#include <hip/hip_runtime.h>
#include <math.h>

#define BB 128
#define CIN 512
#define HW 64
#define OUTC 256
#define EMB 4096
#define DDIM 4096
#define NPIX 8192
#define ES 32

// workspace layout (float offsets)
#define FT_OFF    0          // 8192*256 floats
#define ENC_OFF   2097152    // 8192 ints
#define TSUM_OFF  2105344    // 4096
#define TLOGT_OFF 2109440    // 4096
#define PL_OFF    2113536    // 128*8*64 = 65536
#define PD_OFF    2179072    // 65536

// ---------------- K1: ft[n][o] = feature(b,:,p) . W[o,:] + bias[o] ----------
__global__ __launch_bounds__(256) void k_lda(const float* __restrict__ feat,
                                             const float* __restrict__ w,
                                             const float* __restrict__ bias,
                                             float* __restrict__ ft) {
    __shared__ __align__(16) float As[16 * 64];
    __shared__ __align__(16) float Bs[16 * 64];
    int bx = blockIdx.x;
    int nb = bx >> 2, ob = bx & 3;           // 128 n-tiles (one batch each), 4 o-tiles
    int n0 = nb * 64, o0 = ob * 64;
    int tid = threadIdx.x;
    int tx = tid & 15, ty = tid >> 4;        // tx -> o dir, ty -> pixel dir
    float acc[4][4] = {};
    const float* fbase = feat + (size_t)nb * CIN * HW;
    for (int kt = 0; kt < CIN / 16; ++kt) {
        int c0 = kt * 16;
        {   // A tile: 16c x 64p, contiguous in memory
            int idx = tid * 4;
            *(float4*)&As[idx] = *(const float4*)&fbase[c0 * 64 + idx];
        }
        {   // B tile: w rows o0..o0+63, cols c0..c0+15, store transposed [k][o]
            int oo = tid & 63, kq = tid >> 6;
            float4 wv = *(const float4*)&w[(size_t)(o0 + oo) * CIN + c0 + kq * 4];
            Bs[(kq * 4 + 0) * 64 + oo] = wv.x;
            Bs[(kq * 4 + 1) * 64 + oo] = wv.y;
            Bs[(kq * 4 + 2) * 64 + oo] = wv.z;
            Bs[(kq * 4 + 3) * 64 + oo] = wv.w;
        }
        __syncthreads();
#pragma unroll
        for (int k = 0; k < 16; ++k) {
            float4 a4 = *(float4*)&As[k * 64 + ty * 4];
            float4 b4 = *(float4*)&Bs[k * 64 + tx * 4];
            float av[4] = {a4.x, a4.y, a4.z, a4.w};
            float bv[4] = {b4.x, b4.y, b4.z, b4.w};
#pragma unroll
            for (int i = 0; i < 4; ++i)
#pragma unroll
                for (int j = 0; j < 4; ++j)
                    acc[i][j] = fmaf(av[i], bv[j], acc[i][j]);
        }
        __syncthreads();
    }
    float4 bs4 = *(const float4*)&bias[o0 + tx * 4];
    float bv[4] = {bs4.x, bs4.y, bs4.z, bs4.w};
#pragma unroll
    for (int i = 0; i < 4; ++i) {
        float4 v;
        v.x = acc[i][0] + bv[0];
        v.y = acc[i][1] + bv[1];
        v.z = acc[i][2] + bv[2];
        v.w = acc[i][3] + bv[3];
        *(float4*)&ft[(size_t)(n0 + ty * 4 + i) * OUTC + o0 + tx * 4] = v;
    }
}

// ---------------- K2: enc[n] = cls*32 + argmin_j ||ft_n - c_j||^2 -----------
__global__ __launch_bounds__(256) void k_enc(const float* __restrict__ ft,
                                             const float* __restrict__ cc,
                                             const int* __restrict__ labels,
                                             int* __restrict__ enc) {
    __shared__ __align__(16) float cbuf[ES * OUTC];   // 32 KB
    __shared__ float vred[4 * 64];
    __shared__ int   ired[4 * 64];
    int b = blockIdx.x, tid = threadIdx.x;
    int cls = labels[b];
    const float* cbase = cc + (size_t)cls * ES * OUTC;
    for (int i = tid * 4; i < ES * OUTC; i += 256 * 4)
        *(float4*)&cbuf[i] = *(const float4*)&cbase[i];
    __syncthreads();
    int p = tid & 63, jg = tid >> 6;     // each thread: pixel p, subclasses jg*8..jg*8+7
    const float* xrow = ft + (size_t)(b * 64 + p) * OUTC;
    float sc[8];
#pragma unroll
    for (int jj = 0; jj < 8; ++jj) sc[jj] = 0.f;
    for (int o = 0; o < OUTC; o += 4) {
        float4 x4 = *(const float4*)&xrow[o];
        float m0 = -2.f * x4.x, m1 = -2.f * x4.y, m2 = -2.f * x4.z, m3 = -2.f * x4.w;
#pragma unroll
        for (int jj = 0; jj < 8; ++jj) {
            const float* cr = &cbuf[(jg * 8 + jj) * OUTC + o];
            float s = sc[jj];
            s = fmaf(cr[0], cr[0] + m0, s);
            s = fmaf(cr[1], cr[1] + m1, s);
            s = fmaf(cr[2], cr[2] + m2, s);
            s = fmaf(cr[3], cr[3] + m3, s);
            sc[jj] = s;
        }
    }
    // local argmin, ascending j, strict <  (matches jnp.argmax first-max)
    float best = sc[0]; int bj = jg * 8;
#pragma unroll
    for (int jj = 1; jj < 8; ++jj)
        if (sc[jj] < best) { best = sc[jj]; bj = jg * 8 + jj; }
    vred[jg * 64 + p] = best;
    ired[jg * 64 + p] = bj;
    __syncthreads();
    if (tid < 64) {
        float bv = vred[tid]; int bi = ired[tid];
#pragma unroll
        for (int g = 1; g < 4; ++g) {
            float v = vred[g * 64 + tid];
            if (v < bv) { bv = v; bi = ired[g * 64 + tid]; }
        }
        enc[b * 64 + tid] = cls * ES + bi;
    }
}

// ---------------- K3: per-row sums of teacher_scores ------------------------
__global__ __launch_bounds__(256) void k_rowsum(const float* __restrict__ ts,
                                                float* __restrict__ tsum,
                                                float* __restrict__ tlogt) {
    int e = blockIdx.x, tid = threadIdx.x;
    const float* row = ts + (size_t)e * DDIM;
    float st = 0.f, sl = 0.f;
#pragma unroll
    for (int i = 0; i < 4; ++i) {
        float4 t4 = *(const float4*)&row[tid * 4 + i * 1024];
        float tv[4] = {t4.x, t4.y, t4.z, t4.w};
#pragma unroll
        for (int j = 0; j < 4; ++j) {
            float t = tv[j];
            st += t;
            sl += (t > 0.f) ? t * logf(t) : 0.f;
        }
    }
    for (int off = 32; off; off >>= 1) {
        st += __shfl_down(st, off);
        sl += __shfl_down(sl, off);
    }
    __shared__ float r[8];
    int lane = tid & 63, wv = tid >> 6;
    if (lane == 0) { r[wv] = st; r[4 + wv] = sl; }
    __syncthreads();
    if (tid == 0) {
        tsum[e]  = r[0] + r[1] + r[2] + r[3];
        tlogt[e] = r[4] + r[5] + r[6] + r[7];
    }
}

// ---------------- K4a: single pass over scores: sumexp + dot ----------------
// grid 1024 = (b, q) with q in 0..7 (512 d each); block 256 = 4 waves.
// lane layout: pg = lane&15 -> pixel group (4 consecutive pixels), lg = lane>>4
// per iter: d = q*512 + it*16 + wv*4 + lg; float4 load over p = pg*4..pg*4+3
__global__ __launch_bounds__(256) void k_main(const float* __restrict__ scores,
                                              const float* __restrict__ ts,
                                              const int* __restrict__ enc,
                                              float* __restrict__ pl,
                                              float* __restrict__ pd) {
    __shared__ int enc_s[64];
    __shared__ float redl[4 * 64];
    __shared__ float redd[4 * 64];
    int bx = blockIdx.x;
    int b = bx >> 3, q = bx & 7;
    int tid = threadIdx.x;
    int lane = tid & 63, wv = tid >> 6;
    int pg = lane & 15, lg = lane >> 4;
    if (tid < 64) enc_s[tid] = enc[b * 64 + tid];
    __syncthreads();
    int e0 = enc_s[pg * 4 + 0];
    int e1 = enc_s[pg * 4 + 1];
    int e2 = enc_s[pg * 4 + 2];
    int e3 = enc_s[pg * 4 + 3];
    int d0 = q * 512 + wv * 4 + lg;                     // first d for this lane
    const float* sptr = scores + (size_t)b * DDIM * HW + (size_t)d0 * HW + pg * 4;
    const float* t0 = ts + (size_t)e0 * DDIM + d0;
    const float* t1 = ts + (size_t)e1 * DDIM + d0;
    const float* t2 = ts + (size_t)e2 * DDIM + d0;
    const float* t3 = ts + (size_t)e3 * DDIM + d0;
    float l0 = 0.f, l1 = 0.f, l2 = 0.f, l3 = 0.f;
    float x0 = 0.f, x1 = 0.f, x2 = 0.f, x3 = 0.f;
#pragma unroll 8
    for (int it = 0; it < 32; ++it) {
        float4 s4 = *(const float4*)(sptr + (size_t)it * 16 * HW);
        float tv0 = t0[it * 16];
        float tv1 = t1[it * 16];
        float tv2 = t2[it * 16];
        float tv3 = t3[it * 16];
        l0 += __expf(s4.x);
        l1 += __expf(s4.y);
        l2 += __expf(s4.z);
        l3 += __expf(s4.w);
        x0 = fmaf(tv0, s4.x, x0);
        x1 = fmaf(tv1, s4.y, x1);
        x2 = fmaf(tv2, s4.z, x2);
        x3 = fmaf(tv3, s4.w, x3);
    }
    // reduce across lg (lanes 16 apart share the same pixels)
    l0 += __shfl_xor(l0, 16); l0 += __shfl_xor(l0, 32);
    l1 += __shfl_xor(l1, 16); l1 += __shfl_xor(l1, 32);
    l2 += __shfl_xor(l2, 16); l2 += __shfl_xor(l2, 32);
    l3 += __shfl_xor(l3, 16); l3 += __shfl_xor(l3, 32);
    x0 += __shfl_xor(x0, 16); x0 += __shfl_xor(x0, 32);
    x1 += __shfl_xor(x1, 16); x1 += __shfl_xor(x1, 32);
    x2 += __shfl_xor(x2, 16); x2 += __shfl_xor(x2, 32);
    x3 += __shfl_xor(x3, 16); x3 += __shfl_xor(x3, 32);
    if (lg == 0) {
        redl[wv * 64 + pg * 4 + 0] = l0;
        redl[wv * 64 + pg * 4 + 1] = l1;
        redl[wv * 64 + pg * 4 + 2] = l2;
        redl[wv * 64 + pg * 4 + 3] = l3;
        redd[wv * 64 + pg * 4 + 0] = x0;
        redd[wv * 64 + pg * 4 + 1] = x1;
        redd[wv * 64 + pg * 4 + 2] = x2;
        redd[wv * 64 + pg * 4 + 3] = x3;
    }
    __syncthreads();
    if (tid < 64) {
        float L = redl[tid] + redl[64 + tid] + redl[128 + tid] + redl[192 + tid];
        float D = redd[tid] + redd[64 + tid] + redd[128 + tid] + redd[192 + tid];
        int idx = (b * 8 + q) * 64 + tid;
        pl[idx] = L;
        pd[idx] = D;
    }
}

// ---------------- K4b: merge partials, final loss ---------------------------
__global__ __launch_bounds__(64) void k_final(const float* __restrict__ pl,
                                              const float* __restrict__ pd,
                                              const int* __restrict__ enc,
                                              const float* __restrict__ tsum,
                                              const float* __restrict__ tlogt,
                                              float* __restrict__ out) {
    int b = blockIdx.x, p = threadIdx.x;
    int base = b * 8 * 64 + p;
    float L = 0.f, D = 0.f;
#pragma unroll
    for (int q = 0; q < 8; ++q) {
        L += pl[base + q * 64];
        D += pd[base + q * 64];
    }
    float lse = logf(L);
    int e = enc[b * 64 + p];
    float row = tlogt[e] - D + tsum[e] * lse;
    for (int off = 32; off; off >>= 1) row += __shfl_down(row, off);
    if (p == 0) atomicAdd(out, row * (1.f / 8192.f));
}

extern "C" void kernel_launch(void* const* d_in, const int* in_sizes, int n_in,
                              void* d_out, int out_size, void* d_ws, size_t ws_size,
                              hipStream_t stream) {
    const float* feat   = (const float*)d_in[0];
    const float* scores = (const float*)d_in[1];
    const int*   labels = (const int*)d_in[2];
    const float* ldaw   = (const float*)d_in[3];
    const float* ldab   = (const float*)d_in[4];
    const float* cc     = (const float*)d_in[5];
    const float* ts     = (const float*)d_in[6];
    float* out = (float*)d_out;
    float* ws  = (float*)d_ws;

    float* ft    = ws + FT_OFF;
    int*   enc   = (int*)(ws + ENC_OFF);
    float* tsum  = ws + TSUM_OFF;
    float* tlogt = ws + TLOGT_OFF;
    float* pl    = ws + PL_OFF;
    float* pd    = ws + PD_OFF;

    hipMemsetAsync(out, 0, sizeof(float), stream);

    k_lda   <<<512,  256, 0, stream>>>(feat, ldaw, ldab, ft);
    k_enc   <<<BB,   256, 0, stream>>>(ft, cc, labels, enc);
    k_rowsum<<<EMB,  256, 0, stream>>>(ts, tsum, tlogt);
    k_main  <<<1024, 256, 0, stream>>>(scores, ts, enc, pl, pd);
    k_final <<<BB,    64, 0, stream>>>(pl, pd, enc, tsum, tlogt, out);
}

// Round 3
// 311.577 us; speedup vs baseline: 1.1266x; 1.0698x over previous
//
#include <hip/hip_runtime.h>
#include <math.h>

#define BB 128
#define CIN 512
#define HW 64
#define OUTC 256
#define EMB 4096
#define DDIM 4096
#define ES 32
#define QCH 16          // D-chunks in k_main

// workspace layout (float offsets)
#define FT_OFF    0          // 8192*256
#define ENC_OFF   2097152    // 8192 ints
#define TSUM_OFF  2105344    // 4096
#define TLOGT_OFF 2109440    // 4096
#define FLAGS_OFF 2113536    // 128 ints
#define PL_OFF    2113664    // 128*16*64 = 131072
#define PD_OFF    2244736    // 131072

typedef short short8 __attribute__((ext_vector_type(8)));
typedef float floatx4 __attribute__((ext_vector_type(4)));

__device__ __forceinline__ unsigned short f2bf(float f) {
    unsigned int u = __builtin_bit_cast(unsigned int, f);
    u += 0x7FFFu + ((u >> 16) & 1u);          // RNE; inputs are finite
    return (unsigned short)(u >> 16);
}

// ---------------- K1: ft = feat . W^T + bias, via bf16 MFMA -----------------
// block: (batch nb, o-tile ob) -> 64 pixels x 64 outputs. 4 waves, each 64p x 16o.
// k-permutation psi(q,j): slot s=8q+j <-> c = (s>>1) + 16*(s&1)  (applied to BOTH
// fragments, so the MFMA dot product is unchanged).
__global__ __launch_bounds__(256) void k_lda(const float* __restrict__ feat,
                                             const float* __restrict__ w,
                                             const float* __restrict__ bias,
                                             float* __restrict__ ft) {
    __shared__ unsigned short As[64 * 40];    // row p: 32 slots used, stride 40
    int bx = blockIdx.x;
    int nb = bx >> 2, ob = bx & 3;
    int n0 = nb * 64, o0 = ob * 64;
    int tid = threadIdx.x;
    int lane = tid & 63, wid = tid >> 6;
    int m = lane & 15, q = lane >> 4;         // m -> row/col-in-frag, q -> k-quad
    int cc = tid >> 4;                        // 0..15  (staging: c and c+16)
    int p4 = (tid & 15) * 4;                  // staging: 4 consecutive pixels
    const float* fbase = feat + (size_t)nb * CIN * HW;
    const float* wrow  = w + (size_t)(o0 + wid * 16 + m) * CIN;
    floatx4 acc[4] = {};
    for (int kt = 0; kt < 16; ++kt) {
        int k0 = kt * 32;
        float4 v0 = *(const float4*)(fbase + (size_t)(k0 + cc) * HW + p4);
        float4 v1 = *(const float4*)(fbase + (size_t)(k0 + cc + 16) * HW + p4);
        // b_frag: W at c-offsets {4q..4q+3} and {4q+16..4q+19}, interleaved
        float4 w0 = *(const float4*)(wrow + k0 + 4 * q);
        float4 w1 = *(const float4*)(wrow + k0 + 16 + 4 * q);
        short8 bf;
        bf[0] = (short)f2bf(w0.x); bf[1] = (short)f2bf(w1.x);
        bf[2] = (short)f2bf(w0.y); bf[3] = (short)f2bf(w1.y);
        bf[4] = (short)f2bf(w0.z); bf[5] = (short)f2bf(w1.z);
        bf[6] = (short)f2bf(w0.w); bf[7] = (short)f2bf(w1.w);
        ushort2 pk;
        pk.x = f2bf(v0.x); pk.y = f2bf(v1.x);
        *(ushort2*)&As[(p4 + 0) * 40 + 2 * cc] = pk;
        pk.x = f2bf(v0.y); pk.y = f2bf(v1.y);
        *(ushort2*)&As[(p4 + 1) * 40 + 2 * cc] = pk;
        pk.x = f2bf(v0.z); pk.y = f2bf(v1.z);
        *(ushort2*)&As[(p4 + 2) * 40 + 2 * cc] = pk;
        pk.x = f2bf(v0.w); pk.y = f2bf(v1.w);
        *(ushort2*)&As[(p4 + 3) * 40 + 2 * cc] = pk;
        __syncthreads();
#pragma unroll
        for (int mt = 0; mt < 4; ++mt) {
            short8 af = *(short8*)&As[(mt * 16 + m) * 40 + q * 8];
            acc[mt] = __builtin_amdgcn_mfma_f32_16x16x32_bf16(af, bf, acc[mt], 0, 0, 0);
        }
        __syncthreads();
    }
    float bv = bias[o0 + wid * 16 + m];
#pragma unroll
    for (int mt = 0; mt < 4; ++mt)
#pragma unroll
        for (int r = 0; r < 4; ++r) {
            int p = mt * 16 + q * 4 + r;      // C/D: row = quad*4+reg, col = lane&15
            ft[(size_t)(n0 + p) * OUTC + o0 + wid * 16 + m] = acc[mt][r] + bv;
        }
}

// ---------------- K2: enc[n] = cls*32 + argmin_j ||ft_n - c_j||^2 -----------
__global__ __launch_bounds__(256) void k_enc(const float* __restrict__ ft,
                                             const float* __restrict__ cc,
                                             const int* __restrict__ labels,
                                             int* __restrict__ enc) {
    __shared__ __align__(16) float cbuf[ES * OUTC];   // 32 KB
    __shared__ float vred[4 * 64];
    __shared__ int   ired[4 * 64];
    int b = blockIdx.x, tid = threadIdx.x;
    int cls = labels[b];
    const float* cbase = cc + (size_t)cls * ES * OUTC;
    for (int i = tid * 4; i < ES * OUTC; i += 256 * 4)
        *(float4*)&cbuf[i] = *(const float4*)&cbase[i];
    __syncthreads();
    int p = tid & 63, jg = tid >> 6;
    const float* xrow = ft + (size_t)(b * 64 + p) * OUTC;
    float sc[8];
#pragma unroll
    for (int jj = 0; jj < 8; ++jj) sc[jj] = 0.f;
    for (int o = 0; o < OUTC; o += 4) {
        float4 x4 = *(const float4*)&xrow[o];
        float m0 = -2.f * x4.x, m1 = -2.f * x4.y, m2 = -2.f * x4.z, m3 = -2.f * x4.w;
#pragma unroll
        for (int jj = 0; jj < 8; ++jj) {
            const float* cr = &cbuf[(jg * 8 + jj) * OUTC + o];
            float s = sc[jj];
            s = fmaf(cr[0], cr[0] + m0, s);
            s = fmaf(cr[1], cr[1] + m1, s);
            s = fmaf(cr[2], cr[2] + m2, s);
            s = fmaf(cr[3], cr[3] + m3, s);
            sc[jj] = s;
        }
    }
    float best = sc[0]; int bj = jg * 8;
#pragma unroll
    for (int jj = 1; jj < 8; ++jj)
        if (sc[jj] < best) { best = sc[jj]; bj = jg * 8 + jj; }
    vred[jg * 64 + p] = best;
    ired[jg * 64 + p] = bj;
    __syncthreads();
    if (tid < 64) {
        float bv = vred[tid]; int bi = ired[tid];
#pragma unroll
        for (int g = 1; g < 4; ++g) {
            float v = vred[g * 64 + tid];
            if (v < bv) { bv = v; bi = ired[g * 64 + tid]; }
        }
        enc[b * 64 + tid] = cls * ES + bi;
    }
}

// ---------------- K0: class-presence flags ----------------------------------
__global__ __launch_bounds__(128) void k_flags(const int* __restrict__ labels,
                                               int* __restrict__ flags) {
    int t = threadIdx.x;
    flags[t] = 0;
    __syncthreads();
    flags[labels[t]] = 1;
}

// ---------------- K3: per-row sums of teacher_scores (present classes only) -
__global__ __launch_bounds__(256) void k_rowsum(const float* __restrict__ ts,
                                                const int* __restrict__ flags,
                                                float* __restrict__ tsum,
                                                float* __restrict__ tlogt) {
    int e = blockIdx.x, tid = threadIdx.x;
    if (!flags[e >> 5]) return;
    const float* row = ts + (size_t)e * DDIM;
    float st = 0.f, sl = 0.f;
#pragma unroll
    for (int i = 0; i < 4; ++i) {
        float4 t4 = *(const float4*)&row[tid * 4 + i * 1024];
        float tv[4] = {t4.x, t4.y, t4.z, t4.w};
#pragma unroll
        for (int j = 0; j < 4; ++j) {
            float t = tv[j];
            st += t;
            sl += (t > 0.f) ? t * logf(t) : 0.f;
        }
    }
    for (int off = 32; off; off >>= 1) {
        st += __shfl_down(st, off);
        sl += __shfl_down(sl, off);
    }
    __shared__ float r[8];
    int lane = tid & 63, wv = tid >> 6;
    if (lane == 0) { r[wv] = st; r[4 + wv] = sl; }
    __syncthreads();
    if (tid == 0) {
        tsum[e]  = r[0] + r[1] + r[2] + r[3];
        tlogt[e] = r[4] + r[5] + r[6] + r[7];
    }
}

// ---------------- K4a: single pass over scores: sumexp + dot ----------------
__global__ __launch_bounds__(256) void k_main(const float* __restrict__ scores,
                                              const float* __restrict__ ts,
                                              const int* __restrict__ enc,
                                              float* __restrict__ pl,
                                              float* __restrict__ pd) {
    __shared__ int enc_s[64];
    __shared__ float redl[4 * 64];
    __shared__ float redd[4 * 64];
    int bx = blockIdx.x;
    int b = bx >> 4, q = bx & 15;
    int tid = threadIdx.x;
    int lane = tid & 63, wv = tid >> 6;
    int pg = lane & 15, lg = lane >> 4;
    if (tid < 64) enc_s[tid] = enc[b * 64 + tid];
    __syncthreads();
    int e0 = enc_s[pg * 4 + 0];
    int e1 = enc_s[pg * 4 + 1];
    int e2 = enc_s[pg * 4 + 2];
    int e3 = enc_s[pg * 4 + 3];
    int d0 = q * 256 + wv * 4 + lg;
    const float* sptr = scores + (size_t)b * DDIM * HW + (size_t)d0 * HW + pg * 4;
    const float* t0 = ts + (size_t)e0 * DDIM + d0;
    const float* t1 = ts + (size_t)e1 * DDIM + d0;
    const float* t2 = ts + (size_t)e2 * DDIM + d0;
    const float* t3 = ts + (size_t)e3 * DDIM + d0;
    float l0 = 0.f, l1 = 0.f, l2 = 0.f, l3 = 0.f;
    float x0 = 0.f, x1 = 0.f, x2 = 0.f, x3 = 0.f;
#pragma unroll
    for (int it = 0; it < 16; ++it) {
        float4 s4 = *(const float4*)(sptr + (size_t)it * 16 * HW);
        float tv0 = t0[it * 16];
        float tv1 = t1[it * 16];
        float tv2 = t2[it * 16];
        float tv3 = t3[it * 16];
        l0 += __expf(s4.x);
        l1 += __expf(s4.y);
        l2 += __expf(s4.z);
        l3 += __expf(s4.w);
        x0 = fmaf(tv0, s4.x, x0);
        x1 = fmaf(tv1, s4.y, x1);
        x2 = fmaf(tv2, s4.z, x2);
        x3 = fmaf(tv3, s4.w, x3);
    }
    l0 += __shfl_xor(l0, 16); l0 += __shfl_xor(l0, 32);
    l1 += __shfl_xor(l1, 16); l1 += __shfl_xor(l1, 32);
    l2 += __shfl_xor(l2, 16); l2 += __shfl_xor(l2, 32);
    l3 += __shfl_xor(l3, 16); l3 += __shfl_xor(l3, 32);
    x0 += __shfl_xor(x0, 16); x0 += __shfl_xor(x0, 32);
    x1 += __shfl_xor(x1, 16); x1 += __shfl_xor(x1, 32);
    x2 += __shfl_xor(x2, 16); x2 += __shfl_xor(x2, 32);
    x3 += __shfl_xor(x3, 16); x3 += __shfl_xor(x3, 32);
    if (lg == 0) {
        redl[wv * 64 + pg * 4 + 0] = l0;
        redl[wv * 64 + pg * 4 + 1] = l1;
        redl[wv * 64 + pg * 4 + 2] = l2;
        redl[wv * 64 + pg * 4 + 3] = l3;
        redd[wv * 64 + pg * 4 + 0] = x0;
        redd[wv * 64 + pg * 4 + 1] = x1;
        redd[wv * 64 + pg * 4 + 2] = x2;
        redd[wv * 64 + pg * 4 + 3] = x3;
    }
    __syncthreads();
    if (tid < 64) {
        float L = redl[tid] + redl[64 + tid] + redl[128 + tid] + redl[192 + tid];
        float D = redd[tid] + redd[64 + tid] + redd[128 + tid] + redd[192 + tid];
        int idx = (b * QCH + q) * 64 + tid;
        pl[idx] = L;
        pd[idx] = D;
    }
}

// ---------------- K4b: merge partials, final loss ---------------------------
__global__ __launch_bounds__(64) void k_final(const float* __restrict__ pl,
                                              const float* __restrict__ pd,
                                              const int* __restrict__ enc,
                                              const float* __restrict__ tsum,
                                              const float* __restrict__ tlogt,
                                              float* __restrict__ out) {
    int b = blockIdx.x, p = threadIdx.x;
    int base = b * QCH * 64 + p;
    float L = 0.f, D = 0.f;
#pragma unroll
    for (int q = 0; q < QCH; ++q) {
        L += pl[base + q * 64];
        D += pd[base + q * 64];
    }
    float lse = logf(L);
    int e = enc[b * 64 + p];
    float row = tlogt[e] - D + tsum[e] * lse;
    for (int off = 32; off; off >>= 1) row += __shfl_down(row, off);
    if (p == 0) atomicAdd(out, row * (1.f / 8192.f));
}

extern "C" void kernel_launch(void* const* d_in, const int* in_sizes, int n_in,
                              void* d_out, int out_size, void* d_ws, size_t ws_size,
                              hipStream_t stream) {
    const float* feat   = (const float*)d_in[0];
    const float* scores = (const float*)d_in[1];
    const int*   labels = (const int*)d_in[2];
    const float* ldaw   = (const float*)d_in[3];
    const float* ldab   = (const float*)d_in[4];
    const float* cc     = (const float*)d_in[5];
    const float* ts     = (const float*)d_in[6];
    float* out = (float*)d_out;
    float* ws  = (float*)d_ws;

    float* ft    = ws + FT_OFF;
    int*   enc   = (int*)(ws + ENC_OFF);
    float* tsum  = ws + TSUM_OFF;
    float* tlogt = ws + TLOGT_OFF;
    int*   flags = (int*)(ws + FLAGS_OFF);
    float* pl    = ws + PL_OFF;
    float* pd    = ws + PD_OFF;

    hipMemsetAsync(out, 0, sizeof(float), stream);

    k_flags <<<1,    128, 0, stream>>>(labels, flags);
    k_lda   <<<512,  256, 0, stream>>>(feat, ldaw, ldab, ft);
    k_enc   <<<BB,   256, 0, stream>>>(ft, cc, labels, enc);
    k_rowsum<<<EMB,  256, 0, stream>>>(ts, flags, tsum, tlogt);
    k_main  <<<BB * QCH, 256, 0, stream>>>(scores, ts, enc, pl, pd);
    k_final <<<BB,    64, 0, stream>>>(pl, pd, enc, tsum, tlogt, out);
}

// Round 4
// 306.831 us; speedup vs baseline: 1.1440x; 1.0155x over previous
//
#include <hip/hip_runtime.h>
#include <math.h>

#define BB 128
#define CIN 512
#define HW 64
#define OUTC 256
#define EMB 4096
#define DDIM 4096
#define ES 32
#define QCH 16          // D-chunks in k_main

// workspace layout (float offsets)
#define FT_OFF    0          // 8192*256
#define ENC_OFF   2097152    // 8192 ints
#define TSUM_OFF  2105344    // 4096
#define TLOGT_OFF 2109440    // 4096
#define PL_OFF    2113664    // 128*16*64 = 131072
#define PD_OFF    2244736    // 131072

typedef short short8 __attribute__((ext_vector_type(8)));
typedef float floatx4 __attribute__((ext_vector_type(4)));

__device__ __forceinline__ unsigned short f2bf(float f) {
    unsigned int u = __builtin_bit_cast(unsigned int, f);
    u += 0x7FFFu + ((u >> 16) & 1u);          // RNE; inputs are finite
    return (unsigned short)(u >> 16);
}

// ---------------- K1: ft = feat . W^T + bias, via bf16 MFMA -----------------
// block: (batch nb, o-tile ob) -> 64 pixels x 64 outputs. 4 waves, each 64p x 16o.
// k-permutation psi: slot s=8q+j <-> c = (s>>1) + 16*(s&1), applied to BOTH
// fragments so the MFMA dot product is unchanged.
__global__ __launch_bounds__(256) void k_lda(const float* __restrict__ feat,
                                             const float* __restrict__ w,
                                             const float* __restrict__ bias,
                                             float* __restrict__ ft,
                                             float* __restrict__ out) {
    if (blockIdx.x == 0 && threadIdx.x == 0) *out = 0.f;   // zero loss accumulator
    __shared__ unsigned short As[64 * 40];    // row p: 32 slots used, stride 40
    int bx = blockIdx.x;
    int nb = bx >> 2, ob = bx & 3;
    int n0 = nb * 64, o0 = ob * 64;
    int tid = threadIdx.x;
    int lane = tid & 63, wid = tid >> 6;
    int m = lane & 15, q = lane >> 4;         // m -> col-in-frag, q -> k-quad
    int cc = tid >> 4;                        // 0..15  (staging: c and c+16)
    int p4 = (tid & 15) * 4;                  // staging: 4 consecutive pixels
    const float* fbase = feat + (size_t)nb * CIN * HW;
    const float* wrow  = w + (size_t)(o0 + wid * 16 + m) * CIN;
    floatx4 acc[4] = {};
    for (int kt = 0; kt < 16; ++kt) {
        int k0 = kt * 32;
        float4 v0 = *(const float4*)(fbase + (size_t)(k0 + cc) * HW + p4);
        float4 v1 = *(const float4*)(fbase + (size_t)(k0 + cc + 16) * HW + p4);
        float4 w0 = *(const float4*)(wrow + k0 + 4 * q);
        float4 w1 = *(const float4*)(wrow + k0 + 16 + 4 * q);
        short8 bf;
        bf[0] = (short)f2bf(w0.x); bf[1] = (short)f2bf(w1.x);
        bf[2] = (short)f2bf(w0.y); bf[3] = (short)f2bf(w1.y);
        bf[4] = (short)f2bf(w0.z); bf[5] = (short)f2bf(w1.z);
        bf[6] = (short)f2bf(w0.w); bf[7] = (short)f2bf(w1.w);
        ushort2 pk;
        pk.x = f2bf(v0.x); pk.y = f2bf(v1.x);
        *(ushort2*)&As[(p4 + 0) * 40 + 2 * cc] = pk;
        pk.x = f2bf(v0.y); pk.y = f2bf(v1.y);
        *(ushort2*)&As[(p4 + 1) * 40 + 2 * cc] = pk;
        pk.x = f2bf(v0.z); pk.y = f2bf(v1.z);
        *(ushort2*)&As[(p4 + 2) * 40 + 2 * cc] = pk;
        pk.x = f2bf(v0.w); pk.y = f2bf(v1.w);
        *(ushort2*)&As[(p4 + 3) * 40 + 2 * cc] = pk;
        __syncthreads();
#pragma unroll
        for (int mt = 0; mt < 4; ++mt) {
            short8 af = *(short8*)&As[(mt * 16 + m) * 40 + q * 8];
            acc[mt] = __builtin_amdgcn_mfma_f32_16x16x32_bf16(af, bf, acc[mt], 0, 0, 0);
        }
        __syncthreads();
    }
    float bv = bias[o0 + wid * 16 + m];
#pragma unroll
    for (int mt = 0; mt < 4; ++mt)
#pragma unroll
        for (int r = 0; r < 4; ++r) {
            int p = mt * 16 + q * 4 + r;      // C/D: row = quad*4+reg, col = lane&15
            ft[(size_t)(n0 + p) * OUTC + o0 + wid * 16 + m] = acc[mt][r] + bv;
        }
}

// ---------------- K2: enc[n] = cls*32 + argmin_j ||ft_n - c_j||^2 -----------
__global__ __launch_bounds__(256) void k_enc(const float* __restrict__ ft,
                                             const float* __restrict__ cc,
                                             const int* __restrict__ labels,
                                             int* __restrict__ enc) {
    __shared__ __align__(16) float cbuf[ES * OUTC];   // 32 KB
    __shared__ float vred[4 * 64];
    __shared__ int   ired[4 * 64];
    int b = blockIdx.x, tid = threadIdx.x;
    int cls = labels[b];
    const float* cbase = cc + (size_t)cls * ES * OUTC;
    for (int i = tid * 4; i < ES * OUTC; i += 256 * 4)
        *(float4*)&cbuf[i] = *(const float4*)&cbase[i];
    __syncthreads();
    int p = tid & 63, jg = tid >> 6;
    const float* xrow = ft + (size_t)(b * 64 + p) * OUTC;
    float sc[8];
#pragma unroll
    for (int jj = 0; jj < 8; ++jj) sc[jj] = 0.f;
    for (int o = 0; o < OUTC; o += 4) {
        float4 x4 = *(const float4*)&xrow[o];
        float m0 = -2.f * x4.x, m1 = -2.f * x4.y, m2 = -2.f * x4.z, m3 = -2.f * x4.w;
#pragma unroll
        for (int jj = 0; jj < 8; ++jj) {
            float4 c4 = *(const float4*)&cbuf[(jg * 8 + jj) * OUTC + o];   // LDS b128 broadcast
            float s = sc[jj];
            s = fmaf(c4.x, c4.x + m0, s);
            s = fmaf(c4.y, c4.y + m1, s);
            s = fmaf(c4.z, c4.z + m2, s);
            s = fmaf(c4.w, c4.w + m3, s);
            sc[jj] = s;
        }
    }
    float best = sc[0]; int bj = jg * 8;
#pragma unroll
    for (int jj = 1; jj < 8; ++jj)
        if (sc[jj] < best) { best = sc[jj]; bj = jg * 8 + jj; }
    vred[jg * 64 + p] = best;
    ired[jg * 64 + p] = bj;
    __syncthreads();
    if (tid < 64) {
        float bv = vred[tid]; int bi = ired[tid];
#pragma unroll
        for (int g = 1; g < 4; ++g) {
            float v = vred[g * 64 + tid];
            if (v < bv) { bv = v; bi = ired[g * 64 + tid]; }
        }
        enc[b * 64 + tid] = cls * ES + bi;
    }
}

// ---------------- K3: per-row sums of teacher_scores (present classes only) -
__global__ __launch_bounds__(256) void k_rowsum(const float* __restrict__ ts,
                                                const int* __restrict__ labels,
                                                float* __restrict__ tsum,
                                                float* __restrict__ tlogt) {
    __shared__ int present;
    int e = blockIdx.x, tid = threadIdx.x;
    if (tid == 0) present = 0;
    __syncthreads();
    int cls = e >> 5;
    if (tid < BB && labels[tid] == cls) present = 1;
    __syncthreads();
    if (!present) return;
    const float* row = ts + (size_t)e * DDIM;
    float st = 0.f, sl = 0.f;
#pragma unroll
    for (int i = 0; i < 4; ++i) {
        float4 t4 = *(const float4*)&row[tid * 4 + i * 1024];
        float tv[4] = {t4.x, t4.y, t4.z, t4.w};
#pragma unroll
        for (int j = 0; j < 4; ++j) {
            float t = tv[j];
            st += t;
            sl += (t > 0.f) ? t * logf(t) : 0.f;
        }
    }
    for (int off = 32; off; off >>= 1) {
        st += __shfl_down(st, off);
        sl += __shfl_down(sl, off);
    }
    __shared__ float r[8];
    int lane = tid & 63, wv = tid >> 6;
    if (lane == 0) { r[wv] = st; r[4 + wv] = sl; }
    __syncthreads();
    if (tid == 0) {
        tsum[e]  = r[0] + r[1] + r[2] + r[3];
        tlogt[e] = r[4] + r[5] + r[6] + r[7];
    }
}

// ---------------- K4a: single pass over scores: sumexp + dot ----------------
__global__ __launch_bounds__(256) void k_main(const float* __restrict__ scores,
                                              const float* __restrict__ ts,
                                              const int* __restrict__ enc,
                                              float* __restrict__ pl,
                                              float* __restrict__ pd) {
    __shared__ float redl[4 * 64];
    __shared__ float redd[4 * 64];
    int bx = blockIdx.x;
    int b = bx >> 4, q = bx & 15;
    int tid = threadIdx.x;
    int lane = tid & 63, wv = tid >> 6;
    int pg = lane & 15, lg = lane >> 4;
    const int* eb = enc + b * 64 + pg * 4;
    int e0 = eb[0], e1 = eb[1], e2 = eb[2], e3 = eb[3];
    int d0 = q * 256 + wv * 4 + lg;
    const float* sptr = scores + (size_t)b * DDIM * HW + (size_t)d0 * HW + pg * 4;
    const float* t0 = ts + (size_t)e0 * DDIM + d0;
    const float* t1 = ts + (size_t)e1 * DDIM + d0;
    const float* t2 = ts + (size_t)e2 * DDIM + d0;
    const float* t3 = ts + (size_t)e3 * DDIM + d0;
    float l0 = 0.f, l1 = 0.f, l2 = 0.f, l3 = 0.f;
    float x0 = 0.f, x1 = 0.f, x2 = 0.f, x3 = 0.f;
#pragma unroll
    for (int it = 0; it < 16; ++it) {
        float4 s4 = *(const float4*)(sptr + (size_t)it * 16 * HW);
        float tv0 = t0[it * 16];
        float tv1 = t1[it * 16];
        float tv2 = t2[it * 16];
        float tv3 = t3[it * 16];
        l0 += __expf(s4.x);
        l1 += __expf(s4.y);
        l2 += __expf(s4.z);
        l3 += __expf(s4.w);
        x0 = fmaf(tv0, s4.x, x0);
        x1 = fmaf(tv1, s4.y, x1);
        x2 = fmaf(tv2, s4.z, x2);
        x3 = fmaf(tv3, s4.w, x3);
    }
    l0 += __shfl_xor(l0, 16); l0 += __shfl_xor(l0, 32);
    l1 += __shfl_xor(l1, 16); l1 += __shfl_xor(l1, 32);
    l2 += __shfl_xor(l2, 16); l2 += __shfl_xor(l2, 32);
    l3 += __shfl_xor(l3, 16); l3 += __shfl_xor(l3, 32);
    x0 += __shfl_xor(x0, 16); x0 += __shfl_xor(x0, 32);
    x1 += __shfl_xor(x1, 16); x1 += __shfl_xor(x1, 32);
    x2 += __shfl_xor(x2, 16); x2 += __shfl_xor(x2, 32);
    x3 += __shfl_xor(x3, 16); x3 += __shfl_xor(x3, 32);
    if (lg == 0) {
        redl[wv * 64 + pg * 4 + 0] = l0;
        redl[wv * 64 + pg * 4 + 1] = l1;
        redl[wv * 64 + pg * 4 + 2] = l2;
        redl[wv * 64 + pg * 4 + 3] = l3;
        redd[wv * 64 + pg * 4 + 0] = x0;
        redd[wv * 64 + pg * 4 + 1] = x1;
        redd[wv * 64 + pg * 4 + 2] = x2;
        redd[wv * 64 + pg * 4 + 3] = x3;
    }
    __syncthreads();
    if (tid < 64) {
        float L = redl[tid] + redl[64 + tid] + redl[128 + tid] + redl[192 + tid];
        float D = redd[tid] + redd[64 + tid] + redd[128 + tid] + redd[192 + tid];
        int idx = (b * QCH + q) * 64 + tid;
        pl[idx] = L;
        pd[idx] = D;
    }
}

// ---------------- K4b: merge partials, final loss ---------------------------
__global__ __launch_bounds__(64) void k_final(const float* __restrict__ pl,
                                              const float* __restrict__ pd,
                                              const int* __restrict__ enc,
                                              const float* __restrict__ tsum,
                                              const float* __restrict__ tlogt,
                                              float* __restrict__ out) {
    int b = blockIdx.x, p = threadIdx.x;
    int base = b * QCH * 64 + p;
    float L = 0.f, D = 0.f;
#pragma unroll
    for (int q = 0; q < QCH; ++q) {
        L += pl[base + q * 64];
        D += pd[base + q * 64];
    }
    float lse = logf(L);
    int e = enc[b * 64 + p];
    float row = tlogt[e] - D + tsum[e] * lse;
    for (int off = 32; off; off >>= 1) row += __shfl_down(row, off);
    if (p == 0) atomicAdd(out, row * (1.f / 8192.f));
}

extern "C" void kernel_launch(void* const* d_in, const int* in_sizes, int n_in,
                              void* d_out, int out_size, void* d_ws, size_t ws_size,
                              hipStream_t stream) {
    const float* feat   = (const float*)d_in[0];
    const float* scores = (const float*)d_in[1];
    const int*   labels = (const int*)d_in[2];
    const float* ldaw   = (const float*)d_in[3];
    const float* ldab   = (const float*)d_in[4];
    const float* cc     = (const float*)d_in[5];
    const float* ts     = (const float*)d_in[6];
    float* out = (float*)d_out;
    float* ws  = (float*)d_ws;

    float* ft    = ws + FT_OFF;
    int*   enc   = (int*)(ws + ENC_OFF);
    float* tsum  = ws + TSUM_OFF;
    float* tlogt = ws + TLOGT_OFF;
    float* pl    = ws + PL_OFF;
    float* pd    = ws + PD_OFF;

    k_lda   <<<512,  256, 0, stream>>>(feat, ldaw, ldab, ft, out);
    k_enc   <<<BB,   256, 0, stream>>>(ft, cc, labels, enc);
    k_rowsum<<<EMB,  256, 0, stream>>>(ts, labels, tsum, tlogt);
    k_main  <<<BB * QCH, 256, 0, stream>>>(scores, ts, enc, pl, pd);
    k_final <<<BB,    64, 0, stream>>>(pl, pd, enc, tsum, tlogt, out);
}